// Round 1
// baseline (569.268 us; speedup 1.0000x reference)
//
#include <hip/hip_runtime.h>

// BlockTopK sparsify: per 8-float block of `score`, keep top-4 (stable
// tie-break = lower index treated as smaller in ascending sort, i.e. among
// equal values the earlier-index ones are dropped first), out = x * mask.
// Memory-bound streaming kernel: 768 MiB traffic, target ~130 us.

__global__ __launch_bounds__(256) void sparsify_topk_kernel(
    const float4* __restrict__ x4,
    const float4* __restrict__ s4,
    float4* __restrict__ o4,
    int nblk)  // number of 8-element blocks
{
    int b = blockIdx.x * blockDim.x + threadIdx.x;
    if (b >= nblk) return;

    // Each 8-block = two float4s at indices 2b, 2b+1.
    float4 sa = s4[2 * b];
    float4 sb = s4[2 * b + 1];
    float4 xa = x4[2 * b];
    float4 xb = x4[2 * b + 1];

    float s[8] = {sa.x, sa.y, sa.z, sa.w, sb.x, sb.y, sb.z, sb.w};
    float v[8] = {xa.x, xa.y, xa.z, xa.w, xb.x, xb.y, xb.z, xb.w};
    float o[8];

#pragma unroll
    for (int i = 0; i < 8; ++i) {
        int rank = 0;
#pragma unroll
        for (int j = 0; j < 8; ++j) {
            // stable ascending order: element j precedes i if smaller, or
            // equal with lower index. rank = #elements strictly before i.
            rank += (s[j] < s[i]) || ((s[j] == s[i]) && (j < i));
        }
        // ascending argsort drops first (8-4)=4 entries -> kept iff rank>=4
        o[i] = (rank >= 4) ? v[i] : 0.0f;
    }

    o4[2 * b]     = make_float4(o[0], o[1], o[2], o[3]);
    o4[2 * b + 1] = make_float4(o[4], o[5], o[6], o[7]);
}

extern "C" void kernel_launch(void* const* d_in, const int* in_sizes, int n_in,
                              void* d_out, int out_size, void* d_ws, size_t ws_size,
                              hipStream_t stream) {
    const float4* x4 = (const float4*)d_in[0];
    const float4* s4 = (const float4*)d_in[1];
    float4* o4 = (float4*)d_out;

    int n = in_sizes[0];          // 8192*8192 = 67,108,864
    int nblk = n / 8;             // 8,388,608 blocks of 8

    const int threads = 256;
    int grid = (nblk + threads - 1) / threads;  // 32768
    sparsify_topk_kernel<<<grid, threads, 0, stream>>>(x4, s4, o4, nblk);
}